// Round 1
// baseline (184.392 us; speedup 1.0000x reference)
//
#include <hip/hip_runtime.h>
#include <hip/hip_bf16.h>

// ODEFunc: out[i] = x_N(x_i) + sum_j A[i,j] * ( edgeMLP(x_i, x_j) + wA0*x_i + wA1*x_j )
//
// Structure: one wave per row i. Per 16 j's: build h0 = relu(u(i) + WA0[:,1]*x_j)
// in bf16 (B-fragment), one mfma_f32_16x16x32_bf16 with WA1 as A-fragment
// (K 16->32 zero-padded), then layer-2 dot (WA2) directly on the D-fragment
// (4 fma + 2 shfl_xor). e values staged through per-wave LDS so the A[i,j]
// accumulation runs with coalesced dwordx4 loads.
//
// MFMA layout facts used (HW-verified per guide):
//   A[m][k]: m = lane&15, k = (lane>>4)*8 + elem   (m120)
//   B[k][n]: n = lane&15, k = (lane>>4)*8 + elem   (symmetric, m93/m97 GEMMs)
//   D[m][n]: n = lane&15, m = (lane>>4)*4 + reg    (m89/m91)

#define NN 4096

typedef __attribute__((ext_vector_type(8))) short short8;
typedef __attribute__((ext_vector_type(4))) float f32x4;

__device__ __forceinline__ unsigned bf16_rne(float f) {
    unsigned u = __float_as_uint(f);
    return (u + 0x7fffu + ((u >> 16) & 1u)) >> 16;
}
// truncation-pack two floats to packed bf16x2 (cheap; error budget allows it)
__device__ __forceinline__ unsigned pk_trunc(float lo, float hi) {
    return (__float_as_uint(lo) >> 16) | (__float_as_uint(hi) & 0xffff0000u);
}

__global__ __launch_bounds__(256, 4) void odef_kernel(
    const float* __restrict__ x,  const float* __restrict__ A,
    const float* __restrict__ WA0, const float* __restrict__ bA0,
    const float* __restrict__ WA1, const float* __restrict__ bA1,
    const float* __restrict__ WA2, const float* __restrict__ bA2,
    const float* __restrict__ Wm0, const float* __restrict__ bm0,
    const float* __restrict__ Wm1, const float* __restrict__ bm1,
    const float* __restrict__ wA,  const float* __restrict__ wf,
    float* __restrict__ out)
{
    __shared__ float ebuf[4][256];   // per-wave e staging (no cross-wave use)

    const int tid  = threadIdx.x;
    const int wave = tid >> 6;
    const int lane = tid & 63;
    const int col  = lane & 15;      // MFMA m (A-frag) / n (B-frag, D col)
    const int quad = lane >> 4;
    const int row  = blockIdx.x * 4 + wave;   // row i, one per wave

    const float xi = x[row];

    // ---- A-fragment: WA1[m][k], k = quad*8+e for quads 0,1; zero-pad quads 2,3
    short8 a_frag;
    {
        union { short8 s8; unsigned u[4]; } au;
        #pragma unroll
        for (int p = 0; p < 4; ++p) {
            float lo = 0.f, hi = 0.f;
            if (quad < 2) {
                int k = quad * 8 + p * 2;
                lo = WA1[col * 16 + k];
                hi = WA1[col * 16 + k + 1];
            }
            au.u[p] = bf16_rne(lo) | (bf16_rne(hi) << 16);
        }
        a_frag = au.s8;
    }

    // ---- per-lane h0 constants: u_k(i) = WA0[k,0]*x_i + bA0[k]; w1_k = WA0[k,1]
    float u_frag[8], w1_frag[8];
    #pragma unroll
    for (int e = 0; e < 8; ++e) {
        if (quad < 2) {
            int k = quad * 8 + e;
            u_frag[e]  = fmaf(WA0[2 * k], xi, bA0[k]);
            w1_frag[e] = WA0[2 * k + 1];
        } else { u_frag[e] = 0.f; w1_frag[e] = 0.f; }
    }

    // ---- per-lane layer-2 constants for D rows m = quad*4 + r
    float wa2_frag[4], b1_frag[4];
    #pragma unroll
    for (int r = 0; r < 4; ++r) {
        wa2_frag[r] = WA2[quad * 4 + r];
        b1_frag[r]  = bA1[quad * 4 + r];
    }

    const float wA1s = wA[1];
    const float c0   = bA2[0] + wA[0] * xi;   // bA2 + skip i-term, per-pair constant

    float acc = 0.f;

    for (int j0 = 0; j0 < NN; j0 += 256) {   // 256 j's per macro-iter (16 MFMA groups)
        #pragma unroll
        for (int gg = 0; gg < 4; ++gg) {     // 4 chunks of 4 groups (register pressure)
            short8 bfr[4];
            #pragma unroll
            for (int g4 = 0; g4 < 4; ++g4) {
                int g = gg * 4 + g4;
                float xg = x[j0 + g * 16 + col];    // L1-hot
                union { short8 s8; unsigned u[4]; } bu;
                #pragma unroll
                for (int p = 0; p < 4; ++p) {
                    float lo = fmaxf(fmaf(w1_frag[2 * p],     xg, u_frag[2 * p]),     0.f);
                    float hi = fmaxf(fmaf(w1_frag[2 * p + 1], xg, u_frag[2 * p + 1]), 0.f);
                    bu.u[p] = pk_trunc(lo, hi);
                }
                bfr[g4] = bu.s8;
            }
            f32x4 d1[4];
            #pragma unroll
            for (int g4 = 0; g4 < 4; ++g4) {
                f32x4 z = {0.f, 0.f, 0.f, 0.f};
                d1[g4] = __builtin_amdgcn_mfma_f32_16x16x32_bf16(a_frag, bfr[g4], z, 0, 0, 0);
            }
            #pragma unroll
            for (int g4 = 0; g4 < 4; ++g4) {
                float p = 0.f;
                #pragma unroll
                for (int r = 0; r < 4; ++r)
                    p = fmaf(wa2_frag[r], fmaxf(d1[g4][r] + b1_frag[r], 0.f), p);
                p += __shfl_xor(p, 16);
                p += __shfl_xor(p, 32);           // e_n now in all lanes (n = col)
                if (lane < 16) ebuf[wave][(gg * 4 + g4) * 16 + lane] = p;
            }
        }
        __builtin_amdgcn_wave_barrier();  // keep LDS writes before the read below
        f32x4 e4 = *(const f32x4*)&ebuf[wave][lane * 4];
        f32x4 a4 = *(const f32x4*)(A + (size_t)row * NN + j0 + lane * 4);
        f32x4 x4 = *(const f32x4*)(x + j0 + lane * 4);
        #pragma unroll
        for (int r = 0; r < 4; ++r) {
            float etot = e4[r] + fmaf(wA1s, x4[r], c0);
            acc = fmaf(a4[r], etot, acc);
        }
        __builtin_amdgcn_wave_barrier();  // and the read before next iter's writes
    }

    // ---- wave reduce row sum
    #pragma unroll
    for (int off = 32; off > 0; off >>= 1)
        acc += __shfl_xor(acc, off);

    if (lane == 0) {
        // node MLP: x_N = relu(x*Wm0+bm0)@Wm1 + bm1 + wf*x   (fp32, exact)
        float xn = fmaf(wf[0], xi, bm1[0]);
        #pragma unroll
        for (int h = 0; h < 16; ++h)
            xn = fmaf(Wm1[h], fmaxf(fmaf(Wm0[h], xi, bm0[h]), 0.f), xn);
        out[row] = xn + acc;
    }
}

extern "C" void kernel_launch(void* const* d_in, const int* in_sizes, int n_in,
                              void* d_out, int out_size, void* d_ws, size_t ws_size,
                              hipStream_t stream) {
    const float* x   = (const float*)d_in[1];
    const float* A   = (const float*)d_in[2];
    const float* WA0 = (const float*)d_in[3];
    const float* bA0 = (const float*)d_in[4];
    const float* WA1 = (const float*)d_in[5];
    const float* bA1 = (const float*)d_in[6];
    const float* WA2 = (const float*)d_in[7];
    const float* bA2 = (const float*)d_in[8];
    const float* Wm0 = (const float*)d_in[9];
    const float* bm0 = (const float*)d_in[10];
    const float* Wm1 = (const float*)d_in[11];
    const float* bm1 = (const float*)d_in[12];
    const float* wA  = (const float*)d_in[13];
    const float* wf  = (const float*)d_in[14];
    float* out = (float*)d_out;

    odef_kernel<<<NN / 4, 256, 0, stream>>>(x, A, WA0, bA0, WA1, bA1, WA2, bA2,
                                            Wm0, bm0, Wm1, bm1, wA, wf, out);
}

// Round 2
// 179.715 us; speedup vs baseline: 1.0260x; 1.0260x over previous
//
#include <hip/hip_runtime.h>
#include <hip/hip_bf16.h>

// ODEFunc: out[i] = x_N(x_i) + sum_j A[i,j] * ( edgeMLP(x_i, x_j) + wA0*x_i + wA1*x_j )
//
// R2: 32x32x16 MFMA (K=16 exact, 32 j's per MFMA), bias folded into C-operand,
// v_perm bf16 pack, float2 ops to bait v_pk_fma_f32, 2-wave j-split per row
// for occupancy (grid 2048, ~24 waves/CU).
//
// MFMA layout (32x32x16 bf16):
//   A[m][k]: m = lane&31, k = (lane>>5)*8 + e   (standard CDNA pattern)
//   B[k][n]: n = lane&31, k = (lane>>5)*8 + e
//   D[m][n]: n = lane&31, m = (reg&3) + 8*(reg>>2) + 4*(lane>>5)  (HW-verified m74/m101)
// Only m<16 carries WA1 (rows 16..31 zero; D regs 8..15 ignored).

#define NN 4096

typedef __attribute__((ext_vector_type(8)))  short short8;
typedef __attribute__((ext_vector_type(2)))  float f32x2;
typedef __attribute__((ext_vector_type(4)))  float f32x4;
typedef __attribute__((ext_vector_type(16))) float f32x16;

__device__ __forceinline__ unsigned bf16_rne(float f) {
    unsigned u = __float_as_uint(f);
    return (u + 0x7fffu + ((u >> 16) & 1u)) >> 16;
}

__global__ __launch_bounds__(256, 6) void odef_kernel(
    const float* __restrict__ x,  const float* __restrict__ A,
    const float* __restrict__ WA0, const float* __restrict__ bA0,
    const float* __restrict__ WA1, const float* __restrict__ bA1,
    const float* __restrict__ WA2, const float* __restrict__ bA2,
    const float* __restrict__ Wm0, const float* __restrict__ bm0,
    const float* __restrict__ Wm1, const float* __restrict__ bm1,
    const float* __restrict__ wA,  const float* __restrict__ wf,
    float* __restrict__ out)
{
    __shared__ float ebuf[4][256];   // per-wave e staging
    __shared__ float partial[4];

    const int tid  = threadIdx.x;
    const int wave = tid >> 6;
    const int lane = tid & 63;
    const int n    = lane & 31;      // MFMA col (B n / D n / A m)
    const int half = lane >> 5;      // k-half for A/B, row-half for D
    const int row  = blockIdx.x * 2 + (wave >> 1);   // 2 rows per block
    const int jbase = (wave & 1) * (NN / 2);         // 2 waves split the j range

    const float xi = x[row];

    // ---- A-fragment: WA1[m][k] for m = n (<16), k = half*8 + e; rows >=16 zero
    short8 a_frag;
    {
        union { short8 s8; unsigned u[4]; } au;
        #pragma unroll
        for (int p = 0; p < 4; ++p) {
            float lo = 0.f, hi = 0.f;
            if (n < 16) {
                int k = half * 8 + p * 2;
                lo = WA1[n * 16 + k];
                hi = WA1[n * 16 + k + 1];
            }
            au.u[p] = bf16_rne(lo) | (bf16_rne(hi) << 16);
        }
        a_frag = au.s8;
    }

    // ---- h0 constants for this lane's 8 k's (k = half*8 + 2p + {0,1})
    f32x2 u2[4], w2[4];
    #pragma unroll
    for (int p = 0; p < 4; ++p) {
        int k0 = half * 8 + p * 2;
        u2[p] = (f32x2){ fmaf(WA0[2 * k0],     xi, bA0[k0]),
                         fmaf(WA0[2 * k0 + 2], xi, bA0[k0 + 1]) };
        w2[p] = (f32x2){ WA0[2 * k0 + 1], WA0[2 * k0 + 3] };
    }

    // ---- layer-2 constants + bias-as-C for D regs 0..7 (rows (r&3)+8*(r>>2)+4*half)
    f32x2 wa2_2[4];
    f32x16 cbias;
    #pragma unroll
    for (int r = 0; r < 16; ++r) cbias[r] = 0.f;
    #pragma unroll
    for (int q = 0; q < 4; ++q) {
        int r0 = 2 * q, r1 = 2 * q + 1;
        int m0 = (r0 & 3) + 8 * (r0 >> 2) + 4 * half;
        int m1 = (r1 & 3) + 8 * (r1 >> 2) + 4 * half;
        wa2_2[q] = (f32x2){ WA2[m0], WA2[m1] };
        cbias[r0] = bA1[m0];
        cbias[r1] = bA1[m1];
    }

    const float wA1s = wA[1];
    const float c0   = bA2[0] + wA[0] * xi;
    const f32x2 zero2 = { 0.f, 0.f };

    float acc = 0.f;

    for (int j0 = jbase; j0 < jbase + NN / 2; j0 += 256) {
        #pragma unroll
        for (int g = 0; g < 8; ++g) {            // 8 groups x 32 j's
            float xg = x[j0 + g * 32 + n];       // L1-hot (x = 16 KB)
            f32x2 xg2 = { xg, xg };
            union { short8 s8; unsigned u[4]; } bu;
            #pragma unroll
            for (int p = 0; p < 4; ++p) {
                f32x2 h = __builtin_elementwise_fma(w2[p], xg2, u2[p]);
                h = __builtin_elementwise_max(h, zero2);
                // pack trunc-bf16x2 in one v_perm: {hi[31:16], lo[31:16]}
                bu.u[p] = __builtin_amdgcn_perm(__float_as_uint(h.y),
                                                __float_as_uint(h.x),
                                                0x07060302u);
            }
            f32x16 d = __builtin_amdgcn_mfma_f32_32x32x16_bf16(a_frag, bu.s8, cbias, 0, 0, 0);
            f32x2 pp = zero2;
            #pragma unroll
            for (int q = 0; q < 4; ++q) {        // regs 0..7 only (rows < 16)
                f32x2 dq = { d[2 * q], d[2 * q + 1] };
                dq = __builtin_elementwise_max(dq, zero2);   // relu (bias already in C)
                pp = __builtin_elementwise_fma(wa2_2[q], dq, pp);
            }
            float p = pp.x + pp.y;
            p += __shfl_xor(p, 32);              // combine row-halves for col n
            if (lane < 32) ebuf[wave][g * 32 + n] = p;
        }
        __builtin_amdgcn_wave_barrier();         // LDS writes before reads (same wave set)
        f32x4 e4 = *(const f32x4*)&ebuf[wave][lane * 4];
        f32x4 a4 = *(const f32x4*)(A + (size_t)row * NN + j0 + lane * 4);
        f32x4 x4 = *(const f32x4*)(x + j0 + lane * 4);
        #pragma unroll
        for (int r = 0; r < 4; ++r)
            acc = fmaf(a4[r], e4[r] + fmaf(wA1s, x4[r], c0), acc);
        __builtin_amdgcn_wave_barrier();         // reads before next iter's writes
    }

    // ---- reduce wave, then combine the two j-half waves per row
    #pragma unroll
    for (int off = 32; off > 0; off >>= 1)
        acc += __shfl_xor(acc, off);
    if (lane == 0) partial[wave] = acc;
    __syncthreads();

    if (lane == 0 && (wave & 1) == 0) {
        // node MLP (fp32 exact): x_N = relu(x*Wm0+bm0)@Wm1 + bm1 + wf*x
        float xn = fmaf(wf[0], xi, bm1[0]);
        #pragma unroll
        for (int h = 0; h < 16; ++h)
            xn = fmaf(Wm1[h], fmaxf(fmaf(Wm0[h], xi, bm0[h]), 0.f), xn);
        out[row] = xn + partial[wave] + partial[wave + 1];
    }
}

extern "C" void kernel_launch(void* const* d_in, const int* in_sizes, int n_in,
                              void* d_out, int out_size, void* d_ws, size_t ws_size,
                              hipStream_t stream) {
    const float* x   = (const float*)d_in[1];
    const float* A   = (const float*)d_in[2];
    const float* WA0 = (const float*)d_in[3];
    const float* bA0 = (const float*)d_in[4];
    const float* WA1 = (const float*)d_in[5];
    const float* bA1 = (const float*)d_in[6];
    const float* WA2 = (const float*)d_in[7];
    const float* bA2 = (const float*)d_in[8];
    const float* Wm0 = (const float*)d_in[9];
    const float* bm0 = (const float*)d_in[10];
    const float* Wm1 = (const float*)d_in[11];
    const float* bm1 = (const float*)d_in[12];
    const float* wA  = (const float*)d_in[13];
    const float* wf  = (const float*)d_in[14];
    float* out = (float*)d_out;

    odef_kernel<<<NN / 2, 256, 0, stream>>>(x, A, WA0, bA0, WA1, bA1, WA2, bA2,
                                            Wm0, bm0, Wm1, bm1, wA, wf, out);
}

// Round 3
// 168.920 us; speedup vs baseline: 1.0916x; 1.0639x over previous
//
#include <hip/hip_runtime.h>
#include <hip/hip_bf16.h>

// ODEFunc: out[i] = x_N(x_i) + sum_j A[i,j] * ( edgeMLP(x_i, x_j) + wA0*x_i + wA1*x_j )
//
// R3: in-lane epilogue. Each lane owns D column n (= one j) and 8 of 16 h1
// rows; A_ij distributes into the WA2 dot, so the per-group epilogue is
// relu+fma in-lane with NO shfl / LDS / barriers. Skip term added in half 0
// only (each j is held by 2 lanes). launch_bounds(256,4) to kill the R2
// scratch spill (WRITE_SIZE 16.4 MB -> ~16 KB expected).
//
// MFMA layout (32x32x16 bf16, validated by R2 pass):
//   A[m][k]: m = lane&31, k = (lane>>5)*8 + e
//   B[k][n]: n = lane&31, k = (lane>>5)*8 + e
//   D[m][n]: n = lane&31, m = (reg&3) + 8*(reg>>2) + 4*(lane>>5)
// Only m<16 carries WA1; D regs 8..15 ignored.

#define NN 4096

typedef __attribute__((ext_vector_type(8)))  short short8;
typedef __attribute__((ext_vector_type(2)))  float f32x2;
typedef __attribute__((ext_vector_type(16))) float f32x16;

__device__ __forceinline__ unsigned bf16_rne(float f) {
    unsigned u = __float_as_uint(f);
    return (u + 0x7fffu + ((u >> 16) & 1u)) >> 16;
}

__global__ __launch_bounds__(256, 4) void odef_kernel(
    const float* __restrict__ x,  const float* __restrict__ A,
    const float* __restrict__ WA0, const float* __restrict__ bA0,
    const float* __restrict__ WA1, const float* __restrict__ bA1,
    const float* __restrict__ WA2, const float* __restrict__ bA2,
    const float* __restrict__ Wm0, const float* __restrict__ bm0,
    const float* __restrict__ Wm1, const float* __restrict__ bm1,
    const float* __restrict__ wA,  const float* __restrict__ wf,
    float* __restrict__ out)
{
    __shared__ float partial[4];

    const int tid  = threadIdx.x;
    const int wave = tid >> 6;
    const int lane = tid & 63;
    const int n    = lane & 31;      // MFMA col (B n / D n / A m)
    const int half = lane >> 5;      // k-half (A/B), row-half (D)
    const int row  = blockIdx.x * 2 + (wave >> 1);   // 2 rows per block
    const int jbase = (wave & 1) * (NN / 2);         // 2 waves split the j range

    const float xi = x[row];

    // ---- A-fragment: WA1[m][k] for m = n (<16), k = half*8 + e; rows >=16 zero
    short8 a_frag;
    {
        union { short8 s8; unsigned u[4]; } au;
        #pragma unroll
        for (int p = 0; p < 4; ++p) {
            float lo = 0.f, hi = 0.f;
            if (n < 16) {
                int k = half * 8 + p * 2;
                lo = WA1[n * 16 + k];
                hi = WA1[n * 16 + k + 1];
            }
            au.u[p] = bf16_rne(lo) | (bf16_rne(hi) << 16);
        }
        a_frag = au.s8;
    }

    // ---- h0 constants for this lane's 8 k's (k = half*8 + 2p + {0,1})
    f32x2 u2[4], w2[4];
    #pragma unroll
    for (int p = 0; p < 4; ++p) {
        int k0 = half * 8 + p * 2;
        u2[p] = (f32x2){ fmaf(WA0[2 * k0],     xi, bA0[k0]),
                         fmaf(WA0[2 * k0 + 2], xi, bA0[k0 + 1]) };
        w2[p] = (f32x2){ WA0[2 * k0 + 1], WA0[2 * k0 + 3] };
    }

    // ---- layer-2 weights + bias-as-C for D regs 0..7 (rows (r&3)+8*(r>>2)+4*half)
    f32x2 wa2_2[4];
    f32x16 cbias;
    #pragma unroll
    for (int r = 0; r < 16; ++r) cbias[r] = 0.f;
    #pragma unroll
    for (int q = 0; q < 4; ++q) {
        int r0 = 2 * q, r1 = 2 * q + 1;
        int m0 = (r0 & 3) + 8 * (r0 >> 2) + 4 * half;
        int m1 = (r1 & 3) + 8 * (r1 >> 2) + 4 * half;
        wa2_2[q] = (f32x2){ WA2[m0], WA2[m1] };
        cbias[r0] = bA1[m0];
        cbias[r1] = bA1[m1];
    }

    // skip term: only half 0 adds it (each j is held by both halves)
    const float wA1h = half ? 0.f : wA[1];
    const float c0h  = half ? 0.f : (bA2[0] + wA[0] * xi);
    const f32x2 zero2 = { 0.f, 0.f };

    const float* Arow = A + (size_t)row * NN + jbase;
    const float* xrow = x + jbase;

    float acc = 0.f;

    #pragma unroll 2
    for (int jj = 0; jj < NN / 2; jj += 32) {    // one 32-j group per iter
        float xg  = xrow[jj + n];                 // L1-hot (x = 16 KB)
        float aij = Arow[jj + n];                 // 128 B bcast-pair txn / group
        f32x2 xg2 = { xg, xg };
        union { short8 s8; unsigned u[4]; } bu;
        #pragma unroll
        for (int p = 0; p < 4; ++p) {
            f32x2 h = __builtin_elementwise_fma(w2[p], xg2, u2[p]);
            h = __builtin_elementwise_max(h, zero2);
            bu.u[p] = __builtin_amdgcn_perm(__float_as_uint(h.y),
                                            __float_as_uint(h.x),
                                            0x07060302u);
        }
        f32x16 d = __builtin_amdgcn_mfma_f32_32x32x16_bf16(a_frag, bu.s8, cbias, 0, 0, 0);
        f32x2 pp = { fmaf(wA1h, xg, c0h), 0.f };
        #pragma unroll
        for (int q = 0; q < 4; ++q) {             // regs 0..7 only (rows < 16)
            f32x2 dq = { d[2 * q], d[2 * q + 1] };
            dq = __builtin_elementwise_max(dq, zero2);   // relu (bias already in C)
            pp = __builtin_elementwise_fma(wa2_2[q], dq, pp);
        }
        acc = fmaf(aij, pp.x + pp.y, acc);
    }

    // ---- reduce wave, then combine the two j-half waves per row
    #pragma unroll
    for (int off = 32; off > 0; off >>= 1)
        acc += __shfl_xor(acc, off);
    if (lane == 0) partial[wave] = acc;
    __syncthreads();

    if (lane == 0 && (wave & 1) == 0) {
        // node MLP (fp32 exact): x_N = relu(x*Wm0+bm0)@Wm1 + bm1 + wf*x
        float xn = fmaf(wf[0], xi, bm1[0]);
        #pragma unroll
        for (int h = 0; h < 16; ++h)
            xn = fmaf(Wm1[h], fmaxf(fmaf(Wm0[h], xi, bm0[h]), 0.f), xn);
        out[row] = xn + partial[wave] + partial[wave + 1];
    }
}

extern "C" void kernel_launch(void* const* d_in, const int* in_sizes, int n_in,
                              void* d_out, int out_size, void* d_ws, size_t ws_size,
                              hipStream_t stream) {
    const float* x   = (const float*)d_in[1];
    const float* A   = (const float*)d_in[2];
    const float* WA0 = (const float*)d_in[3];
    const float* bA0 = (const float*)d_in[4];
    const float* WA1 = (const float*)d_in[5];
    const float* bA1 = (const float*)d_in[6];
    const float* WA2 = (const float*)d_in[7];
    const float* bA2 = (const float*)d_in[8];
    const float* Wm0 = (const float*)d_in[9];
    const float* bm0 = (const float*)d_in[10];
    const float* Wm1 = (const float*)d_in[11];
    const float* bm1 = (const float*)d_in[12];
    const float* wA  = (const float*)d_in[13];
    const float* wf  = (const float*)d_in[14];
    float* out = (float*)d_out;

    odef_kernel<<<NN / 2, 256, 0, stream>>>(x, A, WA0, bA0, WA1, bA1, WA2, bA2,
                                            Wm0, bm0, Wm1, bm1, wA, wf, out);
}

// Round 6
// 163.404 us; speedup vs baseline: 1.1284x; 1.0338x over previous
//
#include <hip/hip_runtime.h>
#include <hip/hip_bf16.h>

// ODEFunc: out[i] = x_N(x_i) + sum_j A[i,j] * ( edgeMLP(x_i, x_j) + wA0*x_i + wA1*x_j )
//
// R6 = R5 with v_pk_max_f32 removed (NOT a gfx950 instruction — CDNA packed
// fp32 VOP3P is only fma/mul/add/mov). ReLU = 2x scalar v_max_f32 per pair.
// Kept: (1) register double-buffered pipeline on the A/x stream to hide the
// ~900-cyc HBM latency that capped R3 at VALUBusy ~50%; (2) inline-asm
// v_pk_fma_f32 for h0 build and WA2-dot epilogue (compiler scalarized f32x2).
//
// MFMA layout (32x32x16 bf16, validated by R2/R3 pass):
//   A[m][k]: m = lane&31, k = (lane>>5)*8 + e
//   B[k][n]: n = lane&31, k = (lane>>5)*8 + e
//   D[m][n]: n = lane&31, m = (reg&3) + 8*(reg>>2) + 4*(lane>>5)
// Only m<16 carries WA1; D regs 8..15 ignored. bA1 folded into C-operand.
// In-lane epilogue: A_ij distributes into the WA2 dot; skip term in half 0 only.

#define NN 4096

typedef __attribute__((ext_vector_type(8)))  short short8;
typedef __attribute__((ext_vector_type(2)))  float f32x2;
typedef __attribute__((ext_vector_type(16))) float f32x16;

__device__ __forceinline__ unsigned bf16_rne(float f) {
    unsigned u = __float_as_uint(f);
    return (u + 0x7fffu + ((u >> 16) & 1u)) >> 16;
}

__device__ __forceinline__ f32x2 pk_fma(f32x2 a, f32x2 b, f32x2 c) {
    f32x2 d;
    asm("v_pk_fma_f32 %0, %1, %2, %3" : "=v"(d) : "v"(a), "v"(b), "v"(c));
    return d;
}
__device__ __forceinline__ f32x2 relu2(f32x2 a) {
    return (f32x2){ fmaxf(a.x, 0.f), fmaxf(a.y, 0.f) };   // 2x v_max_f32
}

__global__ __launch_bounds__(256, 4) void odef_kernel(
    const float* __restrict__ x,  const float* __restrict__ A,
    const float* __restrict__ WA0, const float* __restrict__ bA0,
    const float* __restrict__ WA1, const float* __restrict__ bA1,
    const float* __restrict__ WA2, const float* __restrict__ bA2,
    const float* __restrict__ Wm0, const float* __restrict__ bm0,
    const float* __restrict__ Wm1, const float* __restrict__ bm1,
    const float* __restrict__ wA,  const float* __restrict__ wf,
    float* __restrict__ out)
{
    __shared__ float partial[4];

    const int tid  = threadIdx.x;
    const int wave = tid >> 6;
    const int lane = tid & 63;
    const int n    = lane & 31;      // MFMA col (B n / D n / A m)
    const int half = lane >> 5;      // k-half (A/B), row-half (D)
    const int row  = blockIdx.x * 2 + (wave >> 1);   // 2 rows per block
    const int jbase = (wave & 1) * (NN / 2);         // 2 waves split the j range

    const float xi = x[row];

    // ---- A-fragment: WA1[m][k] for m = n (<16), k = half*8 + e; rows >=16 zero
    short8 a_frag;
    {
        union { short8 s8; unsigned u[4]; } au;
        #pragma unroll
        for (int p = 0; p < 4; ++p) {
            float lo = 0.f, hi = 0.f;
            if (n < 16) {
                int k = half * 8 + p * 2;
                lo = WA1[n * 16 + k];
                hi = WA1[n * 16 + k + 1];
            }
            au.u[p] = bf16_rne(lo) | (bf16_rne(hi) << 16);
        }
        a_frag = au.s8;
    }

    // ---- h0 constants for this lane's 8 k's (k = half*8 + 2p + {0,1})
    f32x2 u2[4], w2[4];
    #pragma unroll
    for (int p = 0; p < 4; ++p) {
        int k0 = half * 8 + p * 2;
        u2[p] = (f32x2){ fmaf(WA0[2 * k0],     xi, bA0[k0]),
                         fmaf(WA0[2 * k0 + 2], xi, bA0[k0 + 1]) };
        w2[p] = (f32x2){ WA0[2 * k0 + 1], WA0[2 * k0 + 3] };
    }

    // ---- layer-2 weights + bias-as-C for D regs 0..7 (rows (r&3)+8*(r>>2)+4*half)
    f32x2 wa2_2[4];
    f32x16 cbias;
    #pragma unroll
    for (int r = 0; r < 16; ++r) cbias[r] = 0.f;
    #pragma unroll
    for (int q = 0; q < 4; ++q) {
        int r0 = 2 * q, r1 = 2 * q + 1;
        int m0 = (r0 & 3) + 8 * (r0 >> 2) + 4 * half;
        int m1 = (r1 & 3) + 8 * (r1 >> 2) + 4 * half;
        wa2_2[q] = (f32x2){ WA2[m0], WA2[m1] };
        cbias[r0] = bA1[m0];
        cbias[r1] = bA1[m1];
    }

    // skip term: only half 0 adds it (each j is held by both halves)
    const float wA1h = half ? 0.f : wA[1];
    const float c0h  = half ? 0.f : (bA2[0] + wA[0] * xi);

    const float* Arow = A + (size_t)row * NN + jbase;
    const float* xrow = x + jbase;

    float acc = 0.f;

    // ---- software-pipelined main loop: 8 macro-iters x 256 j (8 groups of 32)
    float xb[2][8], ab[2][8];
    #pragma unroll
    for (int g = 0; g < 8; ++g) {
        xb[0][g] = xrow[g * 32 + n];
        ab[0][g] = Arow[g * 32 + n];
    }

    #pragma unroll
    for (int m = 0; m < 8; ++m) {
        const int cb = m & 1, nb = cb ^ 1;
        const int mn = (m < 7) ? m + 1 : 7;          // last iter: redundant reload
        #pragma unroll
        for (int g = 0; g < 8; ++g) {                // prefetch next macro-iter
            xb[nb][g] = xrow[mn * 256 + g * 32 + n];
            ab[nb][g] = Arow[mn * 256 + g * 32 + n];
        }
        #pragma unroll
        for (int g = 0; g < 8; ++g) {                // compute current macro-iter
            float xg  = xb[cb][g];
            float aij = ab[cb][g];
            f32x2 xg2 = { xg, xg };
            union { short8 s8; unsigned u[4]; } bu;
            #pragma unroll
            for (int p = 0; p < 4; ++p) {
                f32x2 h = relu2(pk_fma(w2[p], xg2, u2[p]));
                bu.u[p] = __builtin_amdgcn_perm(__float_as_uint(h.y),
                                                __float_as_uint(h.x),
                                                0x07060302u);
            }
            union { f32x16 v16; f32x2 v2[8]; } du;
            du.v16 = __builtin_amdgcn_mfma_f32_32x32x16_bf16(a_frag, bu.s8, cbias, 0, 0, 0);
            f32x2 pp = { fmaf(wA1h, xg, c0h), 0.f };
            #pragma unroll
            for (int q = 0; q < 4; ++q)              // regs 0..7 only (rows < 16)
                pp = pk_fma(wa2_2[q], relu2(du.v2[q]), pp);
            acc = fmaf(aij, pp.x + pp.y, acc);
        }
    }

    // ---- reduce wave, then combine the two j-half waves per row
    #pragma unroll
    for (int off = 32; off > 0; off >>= 1)
        acc += __shfl_xor(acc, off);
    if (lane == 0) partial[wave] = acc;
    __syncthreads();

    if (lane == 0 && (wave & 1) == 0) {
        // node MLP (fp32 exact): x_N = relu(x*Wm0+bm0)@Wm1 + bm1 + wf*x
        float xn = fmaf(wf[0], xi, bm1[0]);
        #pragma unroll
        for (int h = 0; h < 16; ++h)
            xn = fmaf(Wm1[h], fmaxf(fmaf(Wm0[h], xi, bm0[h]), 0.f), xn);
        out[row] = xn + partial[wave] + partial[wave + 1];
    }
}

extern "C" void kernel_launch(void* const* d_in, const int* in_sizes, int n_in,
                              void* d_out, int out_size, void* d_ws, size_t ws_size,
                              hipStream_t stream) {
    const float* x   = (const float*)d_in[1];
    const float* A   = (const float*)d_in[2];
    const float* WA0 = (const float*)d_in[3];
    const float* bA0 = (const float*)d_in[4];
    const float* WA1 = (const float*)d_in[5];
    const float* bA1 = (const float*)d_in[6];
    const float* WA2 = (const float*)d_in[7];
    const float* bA2 = (const float*)d_in[8];
    const float* Wm0 = (const float*)d_in[9];
    const float* bm0 = (const float*)d_in[10];
    const float* Wm1 = (const float*)d_in[11];
    const float* bm1 = (const float*)d_in[12];
    const float* wA  = (const float*)d_in[13];
    const float* wf  = (const float*)d_in[14];
    float* out = (float*)d_out;

    odef_kernel<<<NN / 2, 256, 0, stream>>>(x, A, WA0, bA0, WA1, bA1, WA2, bA2,
                                            Wm0, bm0, Wm1, bm1, wA, wf, out);
}

// Round 7
// 162.095 us; speedup vs baseline: 1.1376x; 1.0081x over previous
//
#include <hip/hip_runtime.h>
#include <hip/hip_bf16.h>

// ODEFunc: out[i] = x_N(x_i) + sum_j A[i,j] * ( edgeMLP(x_i, x_j) + wA0*x_i + wA1*x_j )
//
// R7: register-footprint fix. R6's 32-reg prefetch arrays + full 64-group
// unroll pushed unified VGPR+AGPR to ~192 (occupancy 33% = 512/192 waves/SIMD
// exactly), with AGPR-spill accvgpr traffic inflating VALU to ~107 instr/group.
// Now: rolled 16-iter loop, prefetch depth 4 with short-lived transients,
// guarded pointer bump (redundant last reload, no OOB). Target ~96 unified
// regs -> 5 waves/SIMD.
//
// MFMA layout (32x32x16 bf16, validated R2-R6):
//   A[m][k]: m = lane&31, k = (lane>>5)*8 + e
//   B[k][n]: n = lane&31, k = (lane>>5)*8 + e
//   D[m][n]: n = lane&31, m = (reg&3) + 8*(reg>>2) + 4*(lane>>5)
// Only m<16 carries WA1; D regs 8..15 ignored. bA1 folded into C-operand
// (loop-invariant, D!=C so no per-group copy). In-lane epilogue: A_ij
// distributes into the WA2 dot; skip term in half 0 only.

#define NN 4096

typedef __attribute__((ext_vector_type(8)))  short short8;
typedef __attribute__((ext_vector_type(2)))  float f32x2;
typedef __attribute__((ext_vector_type(16))) float f32x16;

__device__ __forceinline__ unsigned bf16_rne(float f) {
    unsigned u = __float_as_uint(f);
    return (u + 0x7fffu + ((u >> 16) & 1u)) >> 16;
}

__device__ __forceinline__ f32x2 pk_fma(f32x2 a, f32x2 b, f32x2 c) {
    f32x2 d;
    asm("v_pk_fma_f32 %0, %1, %2, %3" : "=v"(d) : "v"(a), "v"(b), "v"(c));
    return d;
}
__device__ __forceinline__ f32x2 relu2(f32x2 a) {
    return (f32x2){ fmaxf(a.x, 0.f), fmaxf(a.y, 0.f) };   // 2x v_max_f32
}

__global__ __launch_bounds__(256, 4) void odef_kernel(
    const float* __restrict__ x,  const float* __restrict__ A,
    const float* __restrict__ WA0, const float* __restrict__ bA0,
    const float* __restrict__ WA1, const float* __restrict__ bA1,
    const float* __restrict__ WA2, const float* __restrict__ bA2,
    const float* __restrict__ Wm0, const float* __restrict__ bm0,
    const float* __restrict__ Wm1, const float* __restrict__ bm1,
    const float* __restrict__ wA,  const float* __restrict__ wf,
    float* __restrict__ out)
{
    __shared__ float partial[4];

    const int tid  = threadIdx.x;
    const int wave = tid >> 6;
    const int lane = tid & 63;
    const int n    = lane & 31;      // MFMA col (B n / D n / A m)
    const int half = lane >> 5;      // k-half (A/B), row-half (D)
    const int row  = blockIdx.x * 2 + (wave >> 1);   // 2 rows per block
    const int jbase = (wave & 1) * (NN / 2);         // 2 waves split the j range

    const float xi = x[row];

    // ---- A-fragment: WA1[m][k] for m = n (<16), k = half*8 + e; rows >=16 zero
    short8 a_frag;
    {
        union { short8 s8; unsigned u[4]; } au;
        #pragma unroll
        for (int p = 0; p < 4; ++p) {
            float lo = 0.f, hi = 0.f;
            if (n < 16) {
                int k = half * 8 + p * 2;
                lo = WA1[n * 16 + k];
                hi = WA1[n * 16 + k + 1];
            }
            au.u[p] = bf16_rne(lo) | (bf16_rne(hi) << 16);
        }
        a_frag = au.s8;
    }

    // ---- h0 constants for this lane's 8 k's (k = half*8 + 2p + {0,1})
    f32x2 u2[4], w2[4];
    #pragma unroll
    for (int p = 0; p < 4; ++p) {
        int k0 = half * 8 + p * 2;
        u2[p] = (f32x2){ fmaf(WA0[2 * k0],     xi, bA0[k0]),
                         fmaf(WA0[2 * k0 + 2], xi, bA0[k0 + 1]) };
        w2[p] = (f32x2){ WA0[2 * k0 + 1], WA0[2 * k0 + 3] };
    }

    // ---- layer-2 weights + bias-as-C for D regs 0..7 (rows (r&3)+8*(r>>2)+4*half)
    f32x2 wa2_2[4];
    f32x16 cbias;
    #pragma unroll
    for (int r = 0; r < 16; ++r) cbias[r] = 0.f;
    #pragma unroll
    for (int q = 0; q < 4; ++q) {
        int r0 = 2 * q, r1 = 2 * q + 1;
        int m0 = (r0 & 3) + 8 * (r0 >> 2) + 4 * half;
        int m1 = (r1 & 3) + 8 * (r1 >> 2) + 4 * half;
        wa2_2[q] = (f32x2){ WA2[m0], WA2[m1] };
        cbias[r0] = bA1[m0];
        cbias[r1] = bA1[m1];
    }

    // skip term: only half 0 adds it (each j is held by both halves)
    const float wA1h = half ? 0.f : wA[1];
    const float c0h  = half ? 0.f : (bA2[0] + wA[0] * xi);

    const float* xp = x + jbase;
    const float* ap = A + (size_t)row * NN + jbase;

    float acc = 0.f;

    // ---- prefetch-depth-4 pipeline: 64 groups of 32 j, rolled 16-iter loop
    float xf[4], af[4];
    #pragma unroll
    for (int t = 0; t < 4; ++t) {
        xf[t] = xp[t * 32 + n];
        af[t] = ap[t * 32 + n];
    }

    for (int g0 = 0; g0 < 64; g0 += 4) {
        // next-block base (uniform-select; last iter redundantly reloads)
        const float* xpn = (g0 + 4 < 64) ? xp + 128 : xp;
        const float* apn = (g0 + 4 < 64) ? ap + 128 : ap;
        float xnew[4], anew[4];
        #pragma unroll
        for (int t = 0; t < 4; ++t) {
            xnew[t] = xpn[t * 32 + n];
            anew[t] = apn[t * 32 + n];
        }
        #pragma unroll
        for (int t = 0; t < 4; ++t) {
            float xg  = xf[t];
            float aij = af[t];
            f32x2 xg2 = { xg, xg };
            union { short8 s8; unsigned u[4]; } bu;
            #pragma unroll
            for (int p = 0; p < 4; ++p) {
                f32x2 h = relu2(pk_fma(w2[p], xg2, u2[p]));
                bu.u[p] = __builtin_amdgcn_perm(__float_as_uint(h.y),
                                                __float_as_uint(h.x),
                                                0x07060302u);
            }
            union { f32x16 v16; f32x2 v2[8]; } du;
            du.v16 = __builtin_amdgcn_mfma_f32_32x32x16_bf16(a_frag, bu.s8, cbias, 0, 0, 0);
            f32x2 pp = { fmaf(wA1h, xg, c0h), 0.f };
            #pragma unroll
            for (int q = 0; q < 4; ++q)              // regs 0..7 only (rows < 16)
                pp = pk_fma(wa2_2[q], relu2(du.v2[q]), pp);
            acc = fmaf(aij, pp.x + pp.y, acc);
            xf[t] = xnew[t];
            af[t] = anew[t];
        }
        xp = xpn;
        ap = apn;
    }

    // ---- reduce wave, then combine the two j-half waves per row
    #pragma unroll
    for (int off = 32; off > 0; off >>= 1)
        acc += __shfl_xor(acc, off);
    if (lane == 0) partial[wave] = acc;
    __syncthreads();

    if (lane == 0 && (wave & 1) == 0) {
        // node MLP (fp32 exact): x_N = relu(x*Wm0+bm0)@Wm1 + bm1 + wf*x
        float xn = fmaf(wf[0], xi, bm1[0]);
        #pragma unroll
        for (int h = 0; h < 16; ++h)
            xn = fmaf(Wm1[h], fmaxf(fmaf(Wm0[h], xi, bm0[h]), 0.f), xn);
        out[row] = xn + partial[wave] + partial[wave + 1];
    }
}

extern "C" void kernel_launch(void* const* d_in, const int* in_sizes, int n_in,
                              void* d_out, int out_size, void* d_ws, size_t ws_size,
                              hipStream_t stream) {
    const float* x   = (const float*)d_in[1];
    const float* A   = (const float*)d_in[2];
    const float* WA0 = (const float*)d_in[3];
    const float* bA0 = (const float*)d_in[4];
    const float* WA1 = (const float*)d_in[5];
    const float* bA1 = (const float*)d_in[6];
    const float* WA2 = (const float*)d_in[7];
    const float* bA2 = (const float*)d_in[8];
    const float* Wm0 = (const float*)d_in[9];
    const float* bm0 = (const float*)d_in[10];
    const float* Wm1 = (const float*)d_in[11];
    const float* bm1 = (const float*)d_in[12];
    const float* wA  = (const float*)d_in[13];
    const float* wf  = (const float*)d_in[14];
    float* out = (float*)d_out;

    odef_kernel<<<NN / 2, 256, 0, stream>>>(x, A, WA0, bA0, WA1, bA1, WA2, bA2,
                                            Wm0, bm0, Wm1, bm1, wA, wf, out);
}

// Round 9
// 147.306 us; speedup vs baseline: 1.2518x; 1.1004x over previous
//
#include <hip/hip_runtime.h>
#include <hip/hip_bf16.h>

// ODEFunc: out[i] = x_N(x_i) + sum_j A[i,j] * ( edgeMLP(x_i, x_j) + wA0*x_i + wA1*x_j )
//
// R9 = R8 with the type fix: clang's AMDGPU builtins use __fp16-based
// vectors (cvt_pkrtz returns __fp16 ext_vector(2)); typedef fragments on
// __fp16 instead of _Float16.
// (1) f16 packed h0 build — v_cvt_pkrtz_f16_f32 + v_pk_fma_f16/v_pk_max_f16;
// pk results ARE the B-fragment (no perm/pack step); MFMA = f32_32x32x16_f16
// (identical shape & layout to bf16 variant). Build: 17 -> 9 instr/group.
// (2) pairwise MFMA pipelining: build0,MFMA0,build1,MFMA1 then epilogue0/1 —
// second build covers MFMA0 + accvgpr-read latency.
//
// MFMA layout (32x32x16, validated R2-R7):
//   A[m][k]: m = lane&31, k = (lane>>5)*8 + e
//   B[k][n]: n = lane&31, k = (lane>>5)*8 + e
//   D[m][n]: n = lane&31, m = (reg&3) + 8*(reg>>2) + 4*(lane>>5)
// Only m<16 carries WA1; D regs 8..15 ignored. bA1 folded into C-operand.
// In-lane epilogue: A_ij distributes into the WA2 dot; skip term in half 0 only.

#define NN 4096

typedef __fp16 half8  __attribute__((ext_vector_type(8)));
typedef __fp16 half2v __attribute__((ext_vector_type(2)));
typedef __attribute__((ext_vector_type(2)))  float f32x2;
typedef __attribute__((ext_vector_type(16))) float f32x16;

__device__ __forceinline__ unsigned cvt_pk_f16(float lo, float hi) {
    half2v h = __builtin_amdgcn_cvt_pkrtz(lo, hi);
    return __builtin_bit_cast(unsigned, h);
}
__device__ __forceinline__ unsigned pk_fma_f16(unsigned a, unsigned b, unsigned c) {
    unsigned d;
    asm("v_pk_fma_f16 %0, %1, %2, %3" : "=v"(d) : "v"(a), "v"(b), "v"(c));
    return d;
}
__device__ __forceinline__ unsigned pk_max_f16(unsigned a, unsigned z) {
    unsigned d;
    asm("v_pk_max_f16 %0, %1, %2" : "=v"(d) : "v"(a), "v"(z));
    return d;
}
__device__ __forceinline__ f32x2 pk_fma(f32x2 a, f32x2 b, f32x2 c) {
    f32x2 d;
    asm("v_pk_fma_f32 %0, %1, %2, %3" : "=v"(d) : "v"(a), "v"(b), "v"(c));
    return d;
}
__device__ __forceinline__ f32x2 relu2(f32x2 a) {
    return (f32x2){ fmaxf(a.x, 0.f), fmaxf(a.y, 0.f) };
}

__global__ __launch_bounds__(256, 4) void odef_kernel(
    const float* __restrict__ x,  const float* __restrict__ A,
    const float* __restrict__ WA0, const float* __restrict__ bA0,
    const float* __restrict__ WA1, const float* __restrict__ bA1,
    const float* __restrict__ WA2, const float* __restrict__ bA2,
    const float* __restrict__ Wm0, const float* __restrict__ bm0,
    const float* __restrict__ Wm1, const float* __restrict__ bm1,
    const float* __restrict__ wA,  const float* __restrict__ wf,
    float* __restrict__ out)
{
    __shared__ float partial[4];

    const int tid  = threadIdx.x;
    const int wave = tid >> 6;
    const int lane = tid & 63;
    const int n    = lane & 31;      // MFMA col (B n / D n / A m)
    const int half = lane >> 5;      // k-half (A/B), row-half (D)
    const int row  = blockIdx.x * 2 + (wave >> 1);   // 2 rows per block
    const int jbase = (wave & 1) * (NN / 2);         // 2 waves split the j range

    const float xi = x[row];

    // ---- A-fragment: WA1[m][k] in f16; m = n (<16), k = half*8 + e; rows >=16 zero
    union { half8 h8; unsigned u[4]; } au;
    #pragma unroll
    for (int p = 0; p < 4; ++p) {
        float lo = 0.f, hi = 0.f;
        if (n < 16) {
            int k = half * 8 + p * 2;
            lo = WA1[n * 16 + k];
            hi = WA1[n * 16 + k + 1];
        }
        au.u[p] = cvt_pk_f16(lo, hi);
    }

    // ---- h0 constants, packed f16: u_k(i) = WA0[k,0]*xi + bA0[k]; w1_k = WA0[k,1]
    unsigned u2h[4], w2h[4];
    #pragma unroll
    for (int p = 0; p < 4; ++p) {
        int k0 = half * 8 + p * 2;
        u2h[p] = cvt_pk_f16(fmaf(WA0[2 * k0],     xi, bA0[k0]),
                            fmaf(WA0[2 * k0 + 2], xi, bA0[k0 + 1]));
        w2h[p] = cvt_pk_f16(WA0[2 * k0 + 1], WA0[2 * k0 + 3]);
    }

    // ---- layer-2 weights + bias-as-C for D regs 0..7 (rows (r&3)+8*(r>>2)+4*half)
    f32x2 wa2_2[4];
    f32x16 cbias;
    #pragma unroll
    for (int r = 0; r < 16; ++r) cbias[r] = 0.f;
    #pragma unroll
    for (int q = 0; q < 4; ++q) {
        int r0 = 2 * q, r1 = 2 * q + 1;
        int m0 = (r0 & 3) + 8 * (r0 >> 2) + 4 * half;
        int m1 = (r1 & 3) + 8 * (r1 >> 2) + 4 * half;
        wa2_2[q] = (f32x2){ WA2[m0], WA2[m1] };
        cbias[r0] = bA1[m0];
        cbias[r1] = bA1[m1];
    }

    // skip term: only half 0 adds it (each j is held by both halves)
    const float wA1h = half ? 0.f : wA[1];
    const float c0h  = half ? 0.f : (bA2[0] + wA[0] * xi);
    const unsigned zero16 = 0u;      // packed f16 zero for pk_max

    const float* xp = x + jbase;
    const float* ap = A + (size_t)row * NN + jbase;

    float acc = 0.f;

    // ---- prefetch-depth-4, pairwise-pipelined: 64 groups of 32 j
    float xf[4], af[4];
    #pragma unroll
    for (int t = 0; t < 4; ++t) {
        xf[t] = xp[t * 32 + n];
        af[t] = ap[t * 32 + n];
    }

    for (int g0 = 0; g0 < 64; g0 += 4) {
        const float* xpn = (g0 + 4 < 64) ? xp + 128 : xp;
        const float* apn = (g0 + 4 < 64) ? ap + 128 : ap;
        float xnew[4], anew[4];
        #pragma unroll
        for (int t = 0; t < 4; ++t) {
            xnew[t] = xpn[t * 32 + n];
            anew[t] = apn[t * 32 + n];
        }
        #pragma unroll
        for (int t = 0; t < 4; t += 2) {
            // build + MFMA for group t
            unsigned xgh0 = cvt_pk_f16(xf[t], xf[t]);
            union { half8 h8; unsigned u[4]; } b0;
            #pragma unroll
            for (int p = 0; p < 4; ++p)
                b0.u[p] = pk_max_f16(pk_fma_f16(w2h[p], xgh0, u2h[p]), zero16);
            union { f32x16 v16; f32x2 v2[8]; } d0;
            d0.v16 = __builtin_amdgcn_mfma_f32_32x32x16_f16(au.h8, b0.h8, cbias, 0, 0, 0);
            // build + MFMA for group t+1 (covers MFMA0 + accvgpr latency)
            unsigned xgh1 = cvt_pk_f16(xf[t + 1], xf[t + 1]);
            union { half8 h8; unsigned u[4]; } b1;
            #pragma unroll
            for (int p = 0; p < 4; ++p)
                b1.u[p] = pk_max_f16(pk_fma_f16(w2h[p], xgh1, u2h[p]), zero16);
            union { f32x16 v16; f32x2 v2[8]; } d1;
            d1.v16 = __builtin_amdgcn_mfma_f32_32x32x16_f16(au.h8, b1.h8, cbias, 0, 0, 0);
            // epilogue t
            {
                f32x2 pp = { fmaf(wA1h, xf[t], c0h), 0.f };
                #pragma unroll
                for (int q = 0; q < 4; ++q)          // D regs 0..7 (rows < 16)
                    pp = pk_fma(wa2_2[q], relu2(d0.v2[q]), pp);
                acc = fmaf(af[t], pp.x + pp.y, acc);
            }
            // epilogue t+1
            {
                f32x2 pp = { fmaf(wA1h, xf[t + 1], c0h), 0.f };
                #pragma unroll
                for (int q = 0; q < 4; ++q)
                    pp = pk_fma(wa2_2[q], relu2(d1.v2[q]), pp);
                acc = fmaf(af[t + 1], pp.x + pp.y, acc);
            }
            xf[t] = xnew[t];         af[t] = anew[t];
            xf[t + 1] = xnew[t + 1]; af[t + 1] = anew[t + 1];
        }
        xp = xpn;
        ap = apn;
    }

    // ---- reduce wave, then combine the two j-half waves per row
    #pragma unroll
    for (int off = 32; off > 0; off >>= 1)
        acc += __shfl_xor(acc, off);
    if (lane == 0) partial[wave] = acc;
    __syncthreads();

    if (lane == 0 && (wave & 1) == 0) {
        // node MLP (fp32 exact): x_N = relu(x*Wm0+bm0)@Wm1 + bm1 + wf*x
        float xn = fmaf(wf[0], xi, bm1[0]);
        #pragma unroll
        for (int h = 0; h < 16; ++h)
            xn = fmaf(Wm1[h], fmaxf(fmaf(Wm0[h], xi, bm0[h]), 0.f), xn);
        out[row] = xn + partial[wave] + partial[wave + 1];
    }
}

extern "C" void kernel_launch(void* const* d_in, const int* in_sizes, int n_in,
                              void* d_out, int out_size, void* d_ws, size_t ws_size,
                              hipStream_t stream) {
    const float* x   = (const float*)d_in[1];
    const float* A   = (const float*)d_in[2];
    const float* WA0 = (const float*)d_in[3];
    const float* bA0 = (const float*)d_in[4];
    const float* WA1 = (const float*)d_in[5];
    const float* bA1 = (const float*)d_in[6];
    const float* WA2 = (const float*)d_in[7];
    const float* bA2 = (const float*)d_in[8];
    const float* Wm0 = (const float*)d_in[9];
    const float* bm0 = (const float*)d_in[10];
    const float* Wm1 = (const float*)d_in[11];
    const float* bm1 = (const float*)d_in[12];
    const float* wA  = (const float*)d_in[13];
    const float* wf  = (const float*)d_in[14];
    float* out = (float*)d_out;

    odef_kernel<<<NN / 2, 256, 0, stream>>>(x, A, WA0, bA0, WA1, bA1, WA2, bA2,
                                            Wm0, bm0, Wm1, bm1, wA, wf, out);
}

// Round 10
// 145.606 us; speedup vs baseline: 1.2664x; 1.0117x over previous
//
#include <hip/hip_runtime.h>
#include <hip/hip_bf16.h>

// ODEFunc: out[i] = x_N(x_i) + sum_j A[i,j] * ( edgeMLP(x_i, x_j) + wA0*x_i + wA1*x_j )
//
// R10 = R9 with the f32x2-asm epilogue replaced by plain scalar C.
// Theory: "v"-constrained f32x2 asm operands forced even-aligned VGPR pairs
// + v_accvgpr_read shuttling of the (AGPR-resident) MFMA D — ~16 copies/group,
// matching the 2.4x VALU-instr inflation seen in R9 counters. Plain
// v_max_f32/v_fma_f32 can source AGPRs directly (CDNA2+).
// Kept: f16 packed build (scalar u32 asm operands — no pair-alignment issue),
// pairwise 2-deep MFMA pipeline, prefetch-4, bias folded into C-operand.
//
// MFMA layout (32x32x16, validated R2-R9):
//   A[m][k]: m = lane&31, k = (lane>>5)*8 + e
//   B[k][n]: n = lane&31, k = (lane>>5)*8 + e
//   D[m][n]: n = lane&31, m = (reg&3) + 8*(reg>>2) + 4*(lane>>5)
// Only m<16 carries WA1; D regs 8..15 ignored. In-lane epilogue: A_ij
// distributes into the WA2 dot; skip term in half 0 only.

#define NN 4096

typedef __fp16 half8  __attribute__((ext_vector_type(8)));
typedef __fp16 half2v __attribute__((ext_vector_type(2)));
typedef __attribute__((ext_vector_type(16))) float f32x16;

__device__ __forceinline__ unsigned cvt_pk_f16(float lo, float hi) {
    half2v h = __builtin_amdgcn_cvt_pkrtz(lo, hi);
    return __builtin_bit_cast(unsigned, h);
}
__device__ __forceinline__ unsigned pk_fma_f16(unsigned a, unsigned b, unsigned c) {
    unsigned d;
    asm("v_pk_fma_f16 %0, %1, %2, %3" : "=v"(d) : "v"(a), "v"(b), "v"(c));
    return d;
}
__device__ __forceinline__ unsigned pk_max_f16(unsigned a, unsigned z) {
    unsigned d;
    asm("v_pk_max_f16 %0, %1, %2" : "=v"(d) : "v"(a), "v"(z));
    return d;
}

__global__ __launch_bounds__(256, 4) void odef_kernel(
    const float* __restrict__ x,  const float* __restrict__ A,
    const float* __restrict__ WA0, const float* __restrict__ bA0,
    const float* __restrict__ WA1, const float* __restrict__ bA1,
    const float* __restrict__ WA2, const float* __restrict__ bA2,
    const float* __restrict__ Wm0, const float* __restrict__ bm0,
    const float* __restrict__ Wm1, const float* __restrict__ bm1,
    const float* __restrict__ wA,  const float* __restrict__ wf,
    float* __restrict__ out)
{
    __shared__ float partial[4];

    const int tid  = threadIdx.x;
    const int wave = tid >> 6;
    const int lane = tid & 63;
    const int n    = lane & 31;      // MFMA col (B n / D n / A m)
    const int half = lane >> 5;      // k-half (A/B), row-half (D)
    const int row  = blockIdx.x * 2 + (wave >> 1);   // 2 rows per block
    const int jbase = (wave & 1) * (NN / 2);         // 2 waves split the j range

    const float xi = x[row];

    // ---- A-fragment: WA1[m][k] in f16; m = n (<16), k = half*8 + e; rows >=16 zero
    union { half8 h8; unsigned u[4]; } au;
    #pragma unroll
    for (int p = 0; p < 4; ++p) {
        float lo = 0.f, hi = 0.f;
        if (n < 16) {
            int k = half * 8 + p * 2;
            lo = WA1[n * 16 + k];
            hi = WA1[n * 16 + k + 1];
        }
        au.u[p] = cvt_pk_f16(lo, hi);
    }

    // ---- h0 constants, packed f16: u_k(i) = WA0[k,0]*xi + bA0[k]; w1_k = WA0[k,1]
    unsigned u2h[4], w2h[4];
    #pragma unroll
    for (int p = 0; p < 4; ++p) {
        int k0 = half * 8 + p * 2;
        u2h[p] = cvt_pk_f16(fmaf(WA0[2 * k0],     xi, bA0[k0]),
                            fmaf(WA0[2 * k0 + 2], xi, bA0[k0 + 1]));
        w2h[p] = cvt_pk_f16(WA0[2 * k0 + 1], WA0[2 * k0 + 3]);
    }

    // ---- layer-2 weights + bias-as-C for D regs 0..7 (rows (r&3)+8*(r>>2)+4*half)
    float wa2s[8];
    f32x16 cbias;
    #pragma unroll
    for (int r = 0; r < 16; ++r) cbias[r] = 0.f;
    #pragma unroll
    for (int r = 0; r < 8; ++r) {
        int m = (r & 3) + 8 * (r >> 2) + 4 * half;
        wa2s[r]  = WA2[m];
        cbias[r] = bA1[m];
    }

    // skip term: only half 0 adds it (each j is held by both halves)
    const float wA1h = half ? 0.f : wA[1];
    const float c0h  = half ? 0.f : (bA2[0] + wA[0] * xi);
    const unsigned zero16 = 0u;

    const float* xp = x + jbase;
    const float* ap = A + (size_t)row * NN + jbase;

    float acc = 0.f;

    // ---- prefetch-depth-4, pairwise-pipelined: 64 groups of 32 j
    float xf[4], af[4];
    #pragma unroll
    for (int t = 0; t < 4; ++t) {
        xf[t] = xp[t * 32 + n];
        af[t] = ap[t * 32 + n];
    }

    for (int g0 = 0; g0 < 64; g0 += 4) {
        const float* xpn = (g0 + 4 < 64) ? xp + 128 : xp;
        const float* apn = (g0 + 4 < 64) ? ap + 128 : ap;
        float xnew[4], anew[4];
        #pragma unroll
        for (int t = 0; t < 4; ++t) {
            xnew[t] = xpn[t * 32 + n];
            anew[t] = apn[t * 32 + n];
        }
        #pragma unroll
        for (int t = 0; t < 4; t += 2) {
            // build + MFMA for group t
            unsigned xgh0 = cvt_pk_f16(xf[t], xf[t]);
            union { half8 h8; unsigned u[4]; } b0;
            #pragma unroll
            for (int p = 0; p < 4; ++p)
                b0.u[p] = pk_max_f16(pk_fma_f16(w2h[p], xgh0, u2h[p]), zero16);
            f32x16 d0 = __builtin_amdgcn_mfma_f32_32x32x16_f16(au.h8, b0.h8, cbias, 0, 0, 0);
            // build + MFMA for group t+1 (covers MFMA0 + D-read latency)
            unsigned xgh1 = cvt_pk_f16(xf[t + 1], xf[t + 1]);
            union { half8 h8; unsigned u[4]; } b1;
            #pragma unroll
            for (int p = 0; p < 4; ++p)
                b1.u[p] = pk_max_f16(pk_fma_f16(w2h[p], xgh1, u2h[p]), zero16);
            f32x16 d1 = __builtin_amdgcn_mfma_f32_32x32x16_f16(au.h8, b1.h8, cbias, 0, 0, 0);
            // epilogue t (plain scalar: v_max/v_fma can source AGPR directly)
            {
                float pp = fmaf(wA1h, xf[t], c0h);
                #pragma unroll
                for (int r = 0; r < 8; ++r)          // D regs 0..7 (rows < 16)
                    pp = fmaf(wa2s[r], fmaxf(d0[r], 0.f), pp);
                acc = fmaf(af[t], pp, acc);
            }
            // epilogue t+1
            {
                float pp = fmaf(wA1h, xf[t + 1], c0h);
                #pragma unroll
                for (int r = 0; r < 8; ++r)
                    pp = fmaf(wa2s[r], fmaxf(d1[r], 0.f), pp);
                acc = fmaf(af[t + 1], pp, acc);
            }
            xf[t] = xnew[t];         af[t] = anew[t];
            xf[t + 1] = xnew[t + 1]; af[t + 1] = anew[t + 1];
        }
        xp = xpn;
        ap = apn;
    }

    // ---- reduce wave, then combine the two j-half waves per row
    #pragma unroll
    for (int off = 32; off > 0; off >>= 1)
        acc += __shfl_xor(acc, off);
    if (lane == 0) partial[wave] = acc;
    __syncthreads();

    if (lane == 0 && (wave & 1) == 0) {
        // node MLP (fp32 exact): x_N = relu(x*Wm0+bm0)@Wm1 + bm1 + wf*x
        float xn = fmaf(wf[0], xi, bm1[0]);
        #pragma unroll
        for (int h = 0; h < 16; ++h)
            xn = fmaf(Wm1[h], fmaxf(fmaf(Wm0[h], xi, bm0[h]), 0.f), xn);
        out[row] = xn + partial[wave] + partial[wave + 1];
    }
}

extern "C" void kernel_launch(void* const* d_in, const int* in_sizes, int n_in,
                              void* d_out, int out_size, void* d_ws, size_t ws_size,
                              hipStream_t stream) {
    const float* x   = (const float*)d_in[1];
    const float* A   = (const float*)d_in[2];
    const float* WA0 = (const float*)d_in[3];
    const float* bA0 = (const float*)d_in[4];
    const float* WA1 = (const float*)d_in[5];
    const float* bA1 = (const float*)d_in[6];
    const float* WA2 = (const float*)d_in[7];
    const float* bA2 = (const float*)d_in[8];
    const float* Wm0 = (const float*)d_in[9];
    const float* bm0 = (const float*)d_in[10];
    const float* Wm1 = (const float*)d_in[11];
    const float* bm1 = (const float*)d_in[12];
    const float* wA  = (const float*)d_in[13];
    const float* wf  = (const float*)d_in[14];
    float* out = (float*)d_out;

    odef_kernel<<<NN / 2, 256, 0, stream>>>(x, A, WA0, bA0, WA1, bA1, WA2, bA2,
                                            Wm0, bm0, Wm1, bm1, wA, wf, out);
}